// Round 2
// baseline (439.615 us; speedup 1.0000x reference)
//
#include <hip/hip_runtime.h>
#include <stdint.h>

// MultiHeadAttentionShuffle: BS=4, SL=128, D=512, H=8, DP=64
// Key insight: all logits are gathers of S[b,h,i,j]=qp_i.kp_j/8 (2MB), and the
// softmax max/denominator are permutation-independent prefix scans over S.
// attn[b,t,h,q,k] = E[i,ik[k]] * F[i,t]  (i=idx_q[t,q]) for q<=t,k<=t;
//                 = 1/(t+1) for q>t,k<=t; 0 for k>t.
// Shuffle indices replicate JAX threefry2x32 + stable argsort exactly.
// R1 fix: jax>=0.4.30 defaults jax_threefry_partitionable=True -> uniform bits
// come from per-element 64-bit counters: bits[i] = y0 ^ y1 of tf2x32(key, hi(i)=0, lo(i)=i).

#define BSZ 4
#define SLEN 128
#define DMODEL 512
#define NHEAD 8
#define HDIM 64

// ---------------- threefry2x32 (matches jax._src.prng) ----------------
__device__ __forceinline__ uint32_t rotl32(uint32_t v, int d) {
  return (v << d) | (v >> (32 - d));
}

__device__ __forceinline__ void tf2x32(uint32_t k0, uint32_t k1, uint32_t x0,
                                       uint32_t x1, uint32_t& y0, uint32_t& y1) {
  uint32_t ks2 = k0 ^ k1 ^ 0x1BD11BDAu;
  x0 += k0; x1 += k1;
#define TF_R(r) { x0 += x1; x1 = rotl32(x1, (r)); x1 ^= x0; }
  TF_R(13) TF_R(15) TF_R(26) TF_R(6)
  x0 += k1;  x1 += ks2 + 1u;
  TF_R(17) TF_R(29) TF_R(16) TF_R(24)
  x0 += ks2; x1 += k0 + 2u;
  TF_R(13) TF_R(15) TF_R(26) TF_R(6)
  x0 += k0;  x1 += k1 + 3u;
  TF_R(17) TF_R(29) TF_R(16) TF_R(24)
  x0 += k1;  x1 += ks2 + 4u;
  TF_R(13) TF_R(15) TF_R(26) TF_R(6)
  x0 += ks2; x1 += k0 + 5u;
#undef TF_R
  y0 = x0; y1 = x1;
}

// idx[m][t][p] = index at sorted position p of row t of shuffle matrix m.
// Row t: positions 0..t-1 = stable argsort of uniforms u[t,0..t-1]; p>=t -> p.
__global__ __launch_bounds__(128) void idx_kernel(int* __restrict__ idx) {
  const int m = blockIdx.x;   // 0=q,1=k,2=v
  const int t = blockIdx.y;
  const int j = threadIdx.x;
  __shared__ float u[SLEN];
  // folded key: threefry(key=[0,42], count=[0,m])
  uint32_t fk0, fk1;
  tf2x32(0u, 42u, 0u, (uint32_t)m, fk0, fk1);
  // jax_threefry_partitionable path: element f uses 64-bit counter f,
  // threefry counter pair (hi=0, lo=f); 32-bit output = y0 ^ y1.
  const int flat = t * SLEN + j;
  uint32_t y0, y1;
  tf2x32(fk0, fk1, 0u, (uint32_t)flat, y0, y1);
  uint32_t bits = y0 ^ y1;
  float uu = __uint_as_float((bits >> 9) | 0x3f800000u) - 1.0f;
  u[j] = uu;
  __syncthreads();
  int* row = idx + (m * SLEN + t) * SLEN;
  if (j >= t) {
    row[j] = j;
  } else {
    int rank = 0;
    for (int i = 0; i < t; ++i) {
      float ui = u[i];
      rank += ((ui < uu) || (ui == uu && i < j)) ? 1 : 0;
    }
    row[rank] = j;  // stable: ties broken by original index
  }
}

// ---------------- 512x512x512 fp32 GEMM (C = A@W + bias) ----------------
__device__ __forceinline__ void gemm512_body(const float* __restrict__ A,
                                             const float* __restrict__ W,
                                             const float* __restrict__ bias,
                                             float* __restrict__ C,
                                             float* As /*64*17*/, float* Ws /*16*64*/) {
  const int tid = threadIdx.x;
  const int tx = tid & 15, ty = tid >> 4;
  const int row0 = blockIdx.y * 64, col0 = blockIdx.x * 64;
  const int lr = tid >> 2, lc = (tid & 3) << 2;   // A-tile load coords (64x16)
  const int wr = tid >> 4, wc = (tid & 15) << 2;  // W-tile load coords (16x64)
  float acc[4][4] = {};
  for (int k0 = 0; k0 < 512; k0 += 16) {
    float4 av = *(const float4*)(A + (size_t)(row0 + lr) * 512 + k0 + lc);
    float4 wv = *(const float4*)(W + (size_t)(k0 + wr) * 512 + col0 + wc);
    As[lr * 17 + lc + 0] = av.x; As[lr * 17 + lc + 1] = av.y;
    As[lr * 17 + lc + 2] = av.z; As[lr * 17 + lc + 3] = av.w;
    *(float4*)(Ws + wr * 64 + wc) = wv;
    __syncthreads();
#pragma unroll
    for (int kk = 0; kk < 16; ++kk) {
      float a[4], b[4];
#pragma unroll
      for (int i = 0; i < 4; ++i) a[i] = As[(ty * 4 + i) * 17 + kk];
#pragma unroll
      for (int jj = 0; jj < 4; ++jj) b[jj] = Ws[kk * 64 + tx * 4 + jj];
#pragma unroll
      for (int i = 0; i < 4; ++i)
#pragma unroll
        for (int jj = 0; jj < 4; ++jj) acc[i][jj] += a[i] * b[jj];
    }
    __syncthreads();
  }
#pragma unroll
  for (int i = 0; i < 4; ++i) {
    int r = row0 + ty * 4 + i, c = col0 + tx * 4;
    float4 o;
    o.x = acc[i][0] + bias[c + 0];
    o.y = acc[i][1] + bias[c + 1];
    o.z = acc[i][2] + bias[c + 2];
    o.w = acc[i][3] + bias[c + 3];
    *(float4*)(C + (size_t)r * 512 + c) = o;
  }
}

__global__ __launch_bounds__(256) void proj_kernel(
    const float* __restrict__ q, const float* __restrict__ k, const float* __restrict__ v,
    const float* __restrict__ wq, const float* __restrict__ wk, const float* __restrict__ wv,
    const float* __restrict__ bq, const float* __restrict__ bk, const float* __restrict__ bv,
    float* __restrict__ qp, float* __restrict__ kp, float* __restrict__ vp) {
  __shared__ float As[64 * 17];
  __shared__ float Ws[16 * 64];
  const float* A; const float* W; const float* B; float* C;
  if (blockIdx.z == 0)      { A = q; W = wq; B = bq; C = qp; }
  else if (blockIdx.z == 1) { A = k; W = wk; B = bk; C = kp; }
  else                      { A = v; W = wv; B = bv; C = vp; }
  gemm512_body(A, W, B, C, As, Ws);
}

__global__ __launch_bounds__(256) void dense_kernel(const float* __restrict__ A,
                                                    const float* __restrict__ W,
                                                    const float* __restrict__ B,
                                                    float* __restrict__ C) {
  __shared__ float As[64 * 17];
  __shared__ float Ws[16 * 64];
  gemm512_body(A, W, B, C, As, Ws);
}

// ---------------- S[b,h,i,j] = dot(qp[b,i,h*64:], kp[b,j,h*64:]) / 8 ----------------
__global__ __launch_bounds__(256) void s_kernel(const float* __restrict__ qp,
                                                const float* __restrict__ kp,
                                                float* __restrict__ S) {
  const int h = blockIdx.x, b = blockIdx.y;
  const int tid = threadIdx.x;
  __shared__ float qs[SLEN * 33];
  __shared__ float ks[SLEN * 33];
  const float* qbase = qp + ((size_t)b * SLEN) * DMODEL + h * HDIM;
  const float* kbase = kp + ((size_t)b * SLEN) * DMODEL + h * HDIM;
  const int i0 = (tid >> 4) * 8, j0 = (tid & 15) * 8;
  float acc[8][8] = {};
  for (int d0 = 0; d0 < HDIM; d0 += 32) {
    __syncthreads();
    for (int it = 0; it < 4; ++it) {
      int flat = it * 256 + tid;          // 1024 float4 slots: 128 rows x 8
      int row = flat >> 3;
      int c4 = (flat & 7) << 2;
      float4 a = *(const float4*)(qbase + (size_t)row * DMODEL + d0 + c4);
      float4 bb = *(const float4*)(kbase + (size_t)row * DMODEL + d0 + c4);
      qs[row * 33 + c4 + 0] = a.x;  qs[row * 33 + c4 + 1] = a.y;
      qs[row * 33 + c4 + 2] = a.z;  qs[row * 33 + c4 + 3] = a.w;
      ks[row * 33 + c4 + 0] = bb.x; ks[row * 33 + c4 + 1] = bb.y;
      ks[row * 33 + c4 + 2] = bb.z; ks[row * 33 + c4 + 3] = bb.w;
    }
    __syncthreads();
    for (int d = 0; d < 32; ++d) {
      float a[8], bb[8];
#pragma unroll
      for (int r = 0; r < 8; ++r) a[r] = qs[(i0 + r) * 33 + d];
#pragma unroll
      for (int c = 0; c < 8; ++c) bb[c] = ks[(j0 + c) * 33 + d];
#pragma unroll
      for (int r = 0; r < 8; ++r)
#pragma unroll
        for (int c = 0; c < 8; ++c) acc[r][c] += a[r] * bb[c];
    }
  }
  float* Sb = S + (size_t)(b * NHEAD + h) * SLEN * SLEN;
#pragma unroll
  for (int r = 0; r < 8; ++r) {
    float4 o0, o1;
    o0.x = acc[r][0] * 0.125f; o0.y = acc[r][1] * 0.125f;
    o0.z = acc[r][2] * 0.125f; o0.w = acc[r][3] * 0.125f;
    o1.x = acc[r][4] * 0.125f; o1.y = acc[r][5] * 0.125f;
    o1.z = acc[r][6] * 0.125f; o1.w = acc[r][7] * 0.125f;
    *(float4*)(Sb + (size_t)(i0 + r) * SLEN + j0) = o0;
    *(float4*)(Sb + (size_t)(i0 + r) * SLEN + j0 + 4) = o1;
  }
}

// ------------- E[i,j]=exp(S-M127[i]); F[t,i]=exp(M127-M_t)/L_t (prefix scan) -------------
__global__ __launch_bounds__(128) void ef_kernel(const float* __restrict__ S,
                                                 float* __restrict__ E,
                                                 float* __restrict__ Ft) {
  const int bh = blockIdx.x;   // 0..31
  const int i = threadIdx.x;   // row
  __shared__ float m127s[SLEN];
  const float* Sb = S + (size_t)bh * SLEN * SLEN;
  const float* Srow = Sb + (size_t)i * SLEN;
  float m = -3.402823466e38f;
  for (int j = 0; j < SLEN; ++j) m = fmaxf(m, Srow[j]);
  m127s[i] = m;
  float rm = -3.402823466e38f, rl = 0.f;
  float* Fb = Ft + (size_t)bh * SLEN * SLEN;  // layout [t][i] for coalesced writes
  for (int t = 0; t < SLEN; ++t) {
    float sv = Srow[t];
    float nm = fmaxf(rm, sv);
    rl = rl * __expf(rm - nm) + __expf(sv - nm);
    rm = nm;
    Fb[t * SLEN + i] = __expf(m - nm) / rl;
  }
  __syncthreads();
  float* Eb = E + (size_t)bh * SLEN * SLEN;
  for (int flat = i; flat < SLEN * SLEN; flat += SLEN) {
    int r = flat >> 7;
    Eb[flat] = __expf(Sb[flat] - m127s[r]);
  }
}

// ------------- big kernel: write attn (269MB) + fused eff (q=t row @ V) -------------
__global__ __launch_bounds__(256) void attn_kernel(const float* __restrict__ E,
                                                   const float* __restrict__ Ft,
                                                   const int* __restrict__ idx,
                                                   const float* __restrict__ vp,
                                                   float* __restrict__ attn_out,
                                                   float* __restrict__ eff) {
  const int h = blockIdx.x, t = blockIdx.y, b = blockIdx.z;
  const int tid = threadIdx.x;
  const int wave = tid >> 6, lane = tid & 63;
  __shared__ int iqs[SLEN], iks[SLEN], ivs[SLEN];
  __shared__ float arow[SLEN];
  if (tid < SLEN) {
    iqs[tid] = idx[(0 * SLEN + t) * SLEN + tid];
    iks[tid] = idx[(1 * SLEN + t) * SLEN + tid];
    ivs[tid] = idx[(2 * SLEN + t) * SLEN + tid];
  }
  __syncthreads();
  const int bh = b * NHEAD + h;
  const float* Eb = E + (size_t)bh * SLEN * SLEN;
  const float* Fb = Ft + ((size_t)bh * SLEN + t) * SLEN;  // F[.,t,i]
  const float inv = 1.0f / (float)(t + 1);
  float* obase = attn_out + ((size_t)((b * SLEN + t) * NHEAD + h)) * SLEN * SLEN;
  const int k0 = lane * 2, k1 = lane * 2 + 1;
  for (int q = wave; q < SLEN; q += 4) {
    float2 val;
    if (q <= t) {
      int iq = iqs[q];
      float f = Fb[iq];
      const float* Er = Eb + (size_t)iq * SLEN;
      val.x = (k0 <= t) ? Er[iks[k0]] * f : 0.f;
      val.y = (k1 <= t) ? Er[iks[k1]] * f : 0.f;
    } else {
      val.x = (k0 <= t) ? inv : 0.f;
      val.y = (k1 <= t) ? inv : 0.f;
    }
    *(float2*)(obase + (size_t)q * SLEN + k0) = val;
    if (q == t) { arow[k0] = val.x; arow[k1] = val.y; }
  }
  __syncthreads();
  // eff[b,t,h*64+d] = sum_{k<=t} attn[t,k] * vp[b, idx_v[t,k], h*64+d]
  if (tid < HDIM) {
    const int d = tid;
    const float* vb = vp + (size_t)b * SLEN * DMODEL + h * HDIM + d;
    float acc = 0.f;
    for (int k = 0; k <= t; ++k) acc += arow[k] * vb[(size_t)ivs[k] * DMODEL];
    eff[((size_t)b * SLEN + t) * DMODEL + h * HDIM + d] = acc;
  }
}

extern "C" void kernel_launch(void* const* d_in, const int* in_sizes, int n_in,
                              void* d_out, int out_size, void* d_ws, size_t ws_size,
                              hipStream_t stream) {
  const float* q    = (const float*)d_in[0];
  const float* k    = (const float*)d_in[1];
  const float* v    = (const float*)d_in[2];
  // d_in[3] = mask: recomputed analytically, unused
  const float* wq_w = (const float*)d_in[4];
  const float* wq_b = (const float*)d_in[5];
  const float* wk_w = (const float*)d_in[6];
  const float* wk_b = (const float*)d_in[7];
  const float* wv_w = (const float*)d_in[8];
  const float* wv_b = (const float*)d_in[9];
  const float* dw   = (const float*)d_in[10];
  const float* db   = (const float*)d_in[11];

  float* out  = (float*)d_out;          // 4*128*512 = 262144
  float* attn = out + 262144;           // 4*128*8*128*128

  // workspace layout (floats): idx(49152 ints) qp kp vp (262144 ea) S E Ft (524288 ea) eff(262144)
  int*   idx = (int*)d_ws;
  float* wsf = (float*)d_ws;
  float* qp  = wsf + 49152;
  float* kp  = qp + 262144;
  float* vp  = kp + 262144;
  float* S   = vp + 262144;
  float* E   = S + 524288;
  float* Ft  = E + 524288;
  float* eff = Ft + 524288;
  (void)in_sizes; (void)n_in; (void)out_size; (void)ws_size;

  idx_kernel<<<dim3(3, 128, 1), 128, 0, stream>>>(idx);
  proj_kernel<<<dim3(8, 8, 3), 256, 0, stream>>>(q, k, v, wq_w, wk_w, wv_w,
                                                 wq_b, wk_b, wv_b, qp, kp, vp);
  s_kernel<<<dim3(8, 4, 1), 256, 0, stream>>>(qp, kp, S);
  ef_kernel<<<dim3(32, 1, 1), 128, 0, stream>>>(S, E, Ft);
  attn_kernel<<<dim3(8, 128, 4), 256, 0, stream>>>(E, Ft, idx, vp, attn, eff);
  dense_kernel<<<dim3(8, 8, 1), 256, 0, stream>>>(eff, dw, db, out);
}